// Round 20
// baseline (735.448 us; speedup 1.0000x reference)
//
#include <hip/hip_runtime.h>
#include <hip/hip_bf16.h>

#define NN 200000
#define EE 400000
#define HDIM 256
#define LL 4
#define FEAT 10

typedef unsigned short ushort_t;
typedef unsigned char uchar_t;
typedef __attribute__((ext_vector_type(8))) short bf16x8;
typedef __attribute__((ext_vector_type(8))) unsigned short u16x8;
typedef __attribute__((ext_vector_type(2))) float f32x2;
typedef __attribute__((ext_vector_type(4))) float f32x4;
typedef __attribute__((ext_vector_type(4))) unsigned int u32x4;

__device__ inline ushort_t f2bf(float f) {
    unsigned int u = __builtin_bit_cast(unsigned int, f);
    return (ushort_t)((u + 0x7fffu + ((u >> 16) & 1u)) >> 16);
}
__device__ inline float bf2f(ushort_t s) {
    unsigned int u = ((unsigned int)s) << 16;
    return __builtin_bit_cast(float, u);
}
__device__ inline float silu_f(float v) { return v / (1.0f + __expf(-v)); }

// ---- x / U / e storage: fp8 e4m3 (8 cols -> uint2 = 8 bytes).
// Row layout: slot s (8-col granule) holds true 8-col chunk s ^ (n&7), s in [0,32).
__device__ inline void x8_load(const void* base, size_t idx, float* f) {
    uint2 v = ((const uint2*)base)[idx];
    f32x2 a0 = __builtin_amdgcn_cvt_pk_f32_fp8((int)v.x, false);
    f32x2 a1 = __builtin_amdgcn_cvt_pk_f32_fp8((int)v.x, true);
    f32x2 a2 = __builtin_amdgcn_cvt_pk_f32_fp8((int)v.y, false);
    f32x2 a3 = __builtin_amdgcn_cvt_pk_f32_fp8((int)v.y, true);
    f[0]=a0[0]; f[1]=a0[1]; f[2]=a1[0]; f[3]=a1[1];
    f[4]=a2[0]; f[5]=a2[1]; f[6]=a3[0]; f[7]=a3[1];
}
__device__ inline void x8_store(void* base, size_t idx, const float* f) {
    int t0 = __builtin_amdgcn_cvt_pk_fp8_f32(f[0], f[1], 0, false);
    t0 = __builtin_amdgcn_cvt_pk_fp8_f32(f[2], f[3], t0, true);
    int t1 = __builtin_amdgcn_cvt_pk_fp8_f32(f[4], f[5], 0, false);
    t1 = __builtin_amdgcn_cvt_pk_fp8_f32(f[6], f[7], t1, true);
    uint2 o; o.x = (unsigned int)t0; o.y = (unsigned int)t1;
    ((uint2*)base)[idx] = o;
}

// ---------------- Wf pre-pack: A-operand fragment layout (bf16), single K=32 chunk
__global__ __launch_bounds__(256) void prep_wf_kernel(
    const float* __restrict__ Wf, ushort_t* __restrict__ Wfc)
{
    int idx = blockIdx.x * 256 + threadIdx.x;   // 8192
    if (idx >= 8192) return;
    int e = idx & 7;
    int lane = (idx >> 3) & 63;
    int nf = (idx >> 9) & 1;
    int w8 = idx >> 10;
    int n = w8 * 32 + nf * 16 + (lane & 15);
    int k = (lane >> 4) * 8 + e;
    Wfc[idx] = (k < FEAT) ? f2bf(Wf[k * HDIM + n]) : (ushort_t)0;
}

// ---------------- node init via MFMA (bf16): xb = fp8(LN(silu(emb[z] + feat@Wf + bf)))
__global__ __launch_bounds__(512, 4) void node_init_kernel(
    const int* __restrict__ z, const float* __restrict__ feat,
    const float* __restrict__ emb, const ushort_t* __restrict__ Wfc,
    const float* __restrict__ bfv, const float* __restrict__ g0,
    const float* __restrict__ b0, void* __restrict__ xb)
{
    __shared__ ushort_t sA[64][256];
    __shared__ float sGB[2][HDIM];
    const int tid = threadIdx.x;
    const int m0 = blockIdx.x * 64;
    const int lane = tid & 63;
    const int w = tid >> 6;
    const int lg = lane >> 4, ll = lane & 15;
    const int cb = w * 32;

    if (tid < HDIM) sGB[0][tid] = g0[tid];
    else sGB[1][tid - HDIM] = b0[tid - HDIM];

    f32x4 bvv[2];
    #pragma unroll
    for (int nf = 0; nf < 2; ++nf)
        bvv[nf] = *(const f32x4*)&bfv[cb + nf * 16 + lg * 4];

    bf16x8 wf[2];
    wf[0] = *(const bf16x8*)(Wfc + w * 1024 + lane * 8);
    wf[1] = *(const bf16x8*)(Wfc + w * 1024 + 512 + lane * 8);

    bf16x8 af[4];
    #pragma unroll
    for (int m = 0; m < 4; ++m) {
        int gr = m0 + m * 16 + ll;
        bf16x8 t = {};
        if (lg == 0) {
            #pragma unroll
            for (int j = 0; j < 8; ++j) t[j] = (short)f2bf(feat[gr * FEAT + j]);
        } else if (lg == 1) {
            t[0] = (short)f2bf(feat[gr * FEAT + 8]);
            t[1] = (short)f2bf(feat[gr * FEAT + 9]);
        }
        af[m] = t;
    }

    f32x4 acc[4][2] = {};
    #pragma unroll
    for (int m = 0; m < 4; ++m)
        #pragma unroll
        for (int nf = 0; nf < 2; ++nf)
            acc[m][nf] = __builtin_amdgcn_mfma_f32_16x16x32_bf16(
                wf[nf], af[m], acc[m][nf], 0, 0, 0);

    #pragma unroll
    for (int m = 0; m < 4; ++m) {
        int r = m * 16 + ll, rx = r & 7;
        int zi = z[m0 + r];
        #pragma unroll
        for (int nf = 0; nf < 2; ++nf) {
            int n0 = cb + nf * 16 + lg * 4;
            f32x4 ev = *(const f32x4*)&emb[(size_t)zi * HDIM + n0];
            int chunk = ((cb + nf * 16) >> 3) + (lg >> 1);
            int celloff = ((chunk ^ rx) << 3) + (lg & 1) * 4;
            ushort4 o;
            o.x = f2bf(silu_f(acc[m][nf][0] + ev[0] + bvv[nf][0]));
            o.y = f2bf(silu_f(acc[m][nf][1] + ev[1] + bvv[nf][1]));
            o.z = f2bf(silu_f(acc[m][nf][2] + ev[2] + bvv[nf][2]));
            o.w = f2bf(silu_f(acc[m][nf][3] + ev[3] + bvv[nf][3]));
            *(ushort4*)&sA[r][celloff] = o;
        }
    }
    __syncthreads();

    {
        int rr = tid >> 3, kk = tid & 7;
        int rot = (kk + rr) & 7;
        u16x8 v8[4];
        float s = 0.f, q = 0.f;
        #pragma unroll
        for (int i = 0; i < 4; ++i) {
            int slot = rot + 8 * i;
            v8[i] = *(const u16x8*)&sA[rr][slot << 3];
            #pragma unroll
            for (int j = 0; j < 8; ++j) {
                float v = bf2f(v8[i][j]);
                s += v; q += v * v;
            }
        }
        #pragma unroll
        for (int o = 1; o < 8; o <<= 1) {
            s += __shfl_xor(s, o, 64);
            q += __shfl_xor(q, o, 64);
        }
        float mu = s * (1.0f / HDIM);
        float var = q * (1.0f / HDIM) - mu * mu;
        float rs = rsqrtf(var + 1e-5f);
        size_t rows = ((size_t)(m0 + rr)) << 5;
        #pragma unroll
        for (int i = 0; i < 4; ++i) {
            int slot = rot + 8 * i;
            int chunk = slot ^ (rr & 7);
            float ov[8];
            #pragma unroll
            for (int j = 0; j < 8; ++j)
                ov[j] = (bf2f(v8[i][j]) - mu) * rs * sGB[0][chunk * 8 + j]
                        + sGB[1][chunk * 8 + j];
            x8_store(xb, rows + slot, ov);
        }
    }
}

__global__ __launch_bounds__(256) void batch_out_kernel(
    const int* __restrict__ batch, float* __restrict__ out)
{
    int i = blockIdx.x * 256 + threadIdx.x;
    if (i < NN) out[i] = (float)batch[i];
}

// ---------------- CSR build
__global__ __launch_bounds__(256) void hist_kernel(const int* __restrict__ ei, int* __restrict__ deg)
{
    int i = blockIdx.x * 256 + threadIdx.x;
    if (i < EE) atomicAdd(&deg[ei[EE + i]], 1);
}

__global__ __launch_bounds__(256) void scan_blocks_kernel(
    const int* __restrict__ deg, int* __restrict__ off, int* __restrict__ psum)
{
    int blk = blockIdx.x, t = threadIdx.x;
    int base = blk * 1024 + t * 4;
    int v[4];
    #pragma unroll
    for (int i = 0; i < 4; ++i) v[i] = (base + i < NN) ? deg[base + i] : 0;
    int s = v[0] + v[1] + v[2] + v[3];
    int lane = t & 63, w = t >> 6;
    int ps = s;
    #pragma unroll
    for (int o = 1; o < 64; o <<= 1) { int u = __shfl_up(ps, o, 64); if (lane >= o) ps += u; }
    __shared__ int wt[4];
    if (lane == 63) wt[w] = ps;
    __syncthreads();
    int wbase = 0;
    for (int k = 0; k < w; ++k) wbase += wt[k];
    int run = wbase + ps - s;
    #pragma unroll
    for (int i = 0; i < 4; ++i) {
        if (base + i < NN) off[base + i] = run;
        run += v[i];
    }
    if (t == 255) psum[blk] = wbase + ps;
}

__global__ __launch_bounds__(256) void scan_top_kernel(int* __restrict__ psum, int nb)
{
    int t = threadIdx.x;
    int v = (t < nb) ? psum[t] : 0;
    int lane = t & 63, w = t >> 6;
    int ps = v;
    #pragma unroll
    for (int o = 1; o < 64; o <<= 1) { int u = __shfl_up(ps, o, 64); if (lane >= o) ps += u; }
    __shared__ int wt[4];
    if (lane == 63) wt[w] = ps;
    __syncthreads();
    int wbase = 0;
    for (int k = 0; k < w; ++k) wbase += wt[k];
    if (t < nb) psum[t] = wbase + ps - v;
}

__global__ __launch_bounds__(256) void scan_add_kernel(
    int* __restrict__ off, const int* __restrict__ psum, int* __restrict__ cursor)
{
    int i = blockIdx.x * 256 + threadIdx.x;
    if (i < NN) {
        int o = off[i] + psum[i >> 10];
        off[i] = o;
        cursor[i] = o;
        if (i == NN - 1) off[NN] = EE;
    }
}

// ---------------- scatter + edge MLP fused: 32 lanes/edge
// lane0 claims CSR slot; all lanes compute e = fp8(silu(ea@We+be)) into CSR order.
__global__ __launch_bounds__(256) void scatter_kernel(
    const int* __restrict__ ei, const float* __restrict__ ea,
    const float* __restrict__ We, const float* __restrict__ be,
    int* __restrict__ cursor, int* __restrict__ srcs,
    float4* __restrict__ eaf, void* __restrict__ e16)
{
    int g = (blockIdx.x * 256 + threadIdx.x) >> 5;   // edge index
    if (g >= EE) return;
    int lane = threadIdx.x & 63;
    int nl = threadIdx.x & 31, c0 = nl * 8;
    float4 av = ((const float4*)ea)[g];
    int pos = 0;
    if (nl == 0) {
        int dst = ei[EE + g];
        pos = atomicAdd(&cursor[dst], 1);
    }
    pos = __shfl(pos, lane & 32, 64);
    if (nl == 0) {
        srcs[pos] = ei[g];
        eaf[pos] = av;
    }
    float v[8];
    #pragma unroll
    for (int j = 0; j < 8; ++j) {
        float t = be[c0 + j] + av.x * We[c0 + j] + av.y * We[HDIM + c0 + j]
                + av.z * We[2 * HDIM + c0 + j] + av.w * We[3 * HDIM + c0 + j];
        v[j] = silu_f(t);
    }
    x8_store(e16, ((size_t)pos << 5) + nl, v);
}

// ---------------- weights: W[l][k][n] f32 -> chunk-major per-wave fragment layout, fp8
__global__ __launch_bounds__(256) void prep_w_kernel(
    const float* __restrict__ W1, const float* __restrict__ W2,
    uchar_t* __restrict__ Wc1, uchar_t* __restrict__ Wc2)
{
    int idx = blockIdx.x * 256 + threadIdx.x;   // 2 * 4 * 65536
    int which = idx >> 18;
    int rem = idx & 0x3FFFF;
    int l = rem >> 16;
    int t = rem & 0xFFFF;
    int e = t & 7;
    int lane = (t >> 3) & 63;
    int nf = (t >> 9) & 1;
    int w8 = (t >> 10) & 7;
    int c = (t >> 13) & 7;
    int n = w8 * 32 + nf * 16 + (lane & 15);
    int k = c * 32 + (lane >> 4) * 8 + e;
    const float* W = which ? W2 : W1;
    float v = W[l * 65536 + k * 256 + n];
    uchar_t* Wc = which ? Wc2 : Wc1;
    int pk = __builtin_amdgcn_cvt_pk_fp8_f32(v, v, 0, false);
    Wc[rem] = (uchar_t)(pk & 0xFF);
}

// ---------------- aggregation: U = fp8(x_self + sum relu(x[src]+e)); 32-lane groups
template<int USE_E>
__global__ __launch_bounds__(256) void agg_kernel(
    const int* __restrict__ off, const int* __restrict__ srcs,
    const void* __restrict__ eprec, const float4* __restrict__ eaf,
    const float* __restrict__ We, const float* __restrict__ be,
    const void* __restrict__ xin, void* __restrict__ U)
{
    const int gstride = (gridDim.x * 256) >> 5;
    const int gid0 = (blockIdx.x * 256 + threadIdx.x) >> 5;
    const int nl = threadIdx.x & 31, c0 = nl * 8;
    float wv[4][8], bev[8];
    if (!USE_E) {
        #pragma unroll
        for (int r4 = 0; r4 < 4; ++r4)
            #pragma unroll
            for (int j = 0; j < 8; ++j) wv[r4][j] = We[r4 * HDIM + c0 + j];
        #pragma unroll
        for (int j = 0; j < 8; ++j) bev[j] = be[c0 + j];
    }

    for (int n = gid0; n < NN; n += gstride) {
        float acc[8];
        x8_load(xin, (((size_t)n) << 5) + (nl ^ (n & 7)), acc);
        int beg = off[n], end = off[n + 1];
        if (USE_E) {
            for (int p = beg; p < end; ++p) {
                int src = srcs[p];
                float xg[8], ev[8];
                x8_load(xin, (((size_t)src) << 5) + (nl ^ (src & 7)), xg);
                x8_load(eprec, ((size_t)p << 5) + nl, ev);
                #pragma unroll
                for (int j = 0; j < 8; ++j)
                    acc[j] += fmaxf(xg[j] + ev[j], 0.f);
            }
        } else {
            for (int p = beg; p < end; ++p) {
                int src = srcs[p];
                float4 av = eaf[p];
                float xg[8];
                x8_load(xin, (((size_t)src) << 5) + (nl ^ (src & 7)), xg);
                #pragma unroll
                for (int j = 0; j < 8; ++j) {
                    float e = silu_f(bev[j] + av.x * wv[0][j] + av.y * wv[1][j]
                                            + av.z * wv[2][j] + av.w * wv[3][j]);
                    acc[j] += fmaxf(xg[j] + e, 0.f);
                }
            }
        }
        x8_store(U, (((size_t)n) << 5) + (nl ^ (n & 7)), acc);
    }
}

// ---------------- MLP + LN, full fp8 GEMM path; 2-deep weight prefetch (same 2 buffers)
template<int LAST>
__global__ __launch_bounds__(512, 4) void mlp_kernel(
    const void* __restrict__ U, const uchar_t* __restrict__ Wc1,
    const uchar_t* __restrict__ Wc2, const float* __restrict__ b1,
    const float* __restrict__ b2, const float* __restrict__ lng,
    const float* __restrict__ lnb, const void* __restrict__ xin,
    void* __restrict__ xout, float* __restrict__ xf32)
{
    __shared__ uchar_t sF[64][256];      // 16KB fp8 cells: U -> t -> h
    __shared__ float sGB[2][HDIM];       // 2KB gamma/beta
    const int tid = threadIdx.x;
    const int m0 = blockIdx.x * 64;
    const int lane = tid & 63;
    const int w = tid >> 6;
    const int lg = lane >> 4, ll = lane & 15;
    const int cb = w * 32;

    if (tid < HDIM) sGB[0][tid] = lng[tid];
    else sGB[1][tid - HDIM] = lnb[tid - HDIM];

    f32x4 bv1v[2], bv2v[2];
    #pragma unroll
    for (int nf = 0; nf < 2; ++nf) {
        int nb = cb + nf * 16 + lg * 4;
        bv1v[nf] = *(const f32x4*)&b1[nb];
        bv2v[nf] = *(const f32x4*)&b2[nb];
    }

    // ---- stage U tile: pure 8B copy (fp8 global -> fp8 LDS, layout identical)
    {
        const uint2* Uq = (const uint2*)U + (((size_t)m0) << 5);
        uint2* sQ = (uint2*)&sF[0][0];
        #pragma unroll
        for (int it = 0; it < 4; ++it) {
            int idx = tid + it * 512;
            sQ[idx] = Uq[idx];
        }
    }
    __syncthreads();

    f32x4 acc[4][2] = {};
    const uchar_t* wp1 = Wc1 + w * 1024 + lane * 8;
    const uchar_t* wp2 = Wc2 + w * 1024 + lane * 8;
    long long wbuf[2][2];
    wbuf[0][0] = *(const long long*)(wp1);
    wbuf[0][1] = *(const long long*)(wp1 + 512);
    wbuf[1][0] = *(const long long*)(wp1 + 8192);
    wbuf[1][1] = *(const long long*)(wp1 + 8192 + 512);

    // ---- GEMM1 (fp8): use wbuf[p&1]; then load chunk p+2 into wbuf[p&1]
    // (p=6 loads W2c0, p=7 loads W2c1 -> covered by t-phase)
    #pragma unroll
    for (int p = 0; p < 8; ++p) {
        long long af[4];
        #pragma unroll
        for (int m = 0; m < 4; ++m) {
            int r = m * 16 + ll;
            af[m] = *(const long long*)&sF[r][(((p * 4 + lg) ^ (r & 7)) << 3)];
        }
        #pragma unroll
        for (int m = 0; m < 4; ++m)
            #pragma unroll
            for (int nf = 0; nf < 2; ++nf)
                acc[m][nf] = __builtin_amdgcn_mfma_f32_16x16x32_fp8_fp8(
                    wbuf[p & 1][nf], af[m], acc[m][nf], 0, 0, 0);
        const uchar_t* nsrc = (p < 6) ? (wp1 + (p + 2) * 8192) : (wp2 + (p - 6) * 8192);
        wbuf[p & 1][0] = *(const long long*)(nsrc);
        wbuf[p & 1][1] = *(const long long*)(nsrc + 512);
    }
    __syncthreads();   // all waves done reading sF(U)

    // ---- t = fp8(silu(acc + b1)) -> sF (4B packs); reset acc
    #pragma unroll
    for (int m = 0; m < 4; ++m) {
        int r = m * 16 + ll, rx = r & 7;
        #pragma unroll
        for (int nf = 0; nf < 2; ++nf) {
            int chunk = ((cb + nf * 16) >> 3) + (lg >> 1);
            int boff = ((chunk ^ rx) << 3) + (lg & 1) * 4;
            float v0 = silu_f(acc[m][nf][0] + bv1v[nf][0]);
            float v1 = silu_f(acc[m][nf][1] + bv1v[nf][1]);
            float v2 = silu_f(acc[m][nf][2] + bv1v[nf][2]);
            float v3 = silu_f(acc[m][nf][3] + bv1v[nf][3]);
            int pk = __builtin_amdgcn_cvt_pk_fp8_f32(v0, v1, 0, false);
            pk = __builtin_amdgcn_cvt_pk_fp8_f32(v2, v3, pk, true);
            *(unsigned int*)&sF[r][boff] = (unsigned int)pk;
            acc[m][nf][0] = 0.f; acc[m][nf][1] = 0.f;
            acc[m][nf][2] = 0.f; acc[m][nf][3] = 0.f;
        }
    }
    __syncthreads();   // t visible

    // ---- GEMM2 (fp8): wbuf holds W2 c0,c1; load p+2 after use
    #pragma unroll
    for (int p = 0; p < 8; ++p) {
        long long af[4];
        #pragma unroll
        for (int m = 0; m < 4; ++m) {
            int r = m * 16 + ll;
            af[m] = *(const long long*)&sF[r][(((p * 4 + lg) ^ (r & 7)) << 3)];
        }
        #pragma unroll
        for (int m = 0; m < 4; ++m)
            #pragma unroll
            for (int nf = 0; nf < 2; ++nf)
                acc[m][nf] = __builtin_amdgcn_mfma_f32_16x16x32_fp8_fp8(
                    wbuf[p & 1][nf], af[m], acc[m][nf], 0, 0, 0);
        if (p < 6) {
            const uchar_t* nsrc = wp2 + (p + 2) * 8192;
            wbuf[p & 1][0] = *(const long long*)(nsrc);
            wbuf[p & 1][1] = *(const long long*)(nsrc + 512);
        }
    }
    __syncthreads();   // all waves done reading sF(t)

    // ---- h = fp8(acc + b2) -> sF cells
    #pragma unroll
    for (int m = 0; m < 4; ++m) {
        int r = m * 16 + ll, rx = r & 7;
        #pragma unroll
        for (int nf = 0; nf < 2; ++nf) {
            int chunk = ((cb + nf * 16) >> 3) + (lg >> 1);
            int boff = ((chunk ^ rx) << 3) + (lg & 1) * 4;
            float v0 = acc[m][nf][0] + bv2v[nf][0];
            float v1 = acc[m][nf][1] + bv2v[nf][1];
            float v2 = acc[m][nf][2] + bv2v[nf][2];
            float v3 = acc[m][nf][3] + bv2v[nf][3];
            int pk = __builtin_amdgcn_cvt_pk_fp8_f32(v0, v1, 0, false);
            pk = __builtin_amdgcn_cvt_pk_fp8_f32(v2, v3, pk, true);
            *(unsigned int*)&sF[r][boff] = (unsigned int)pk;
        }
    }
    __syncthreads();   // h visible

    // ---- row-pass LN: 8 thr/row, rotation swizzle; residual x from global (fp8)
    {
        int rr = tid >> 3, kk = tid & 7;
        int rot = (kk + rr) & 7;
        size_t rows = ((size_t)(m0 + rr)) << 5;
        float vv[4][8];
        float s = 0.f, q = 0.f;
        #pragma unroll
        for (int i = 0; i < 4; ++i) {
            int slot = rot + 8 * i;
            uint2 hq = *(const uint2*)&sF[rr][slot << 3];
            f32x2 h0 = __builtin_amdgcn_cvt_pk_f32_fp8((int)hq.x, false);
            f32x2 h1 = __builtin_amdgcn_cvt_pk_f32_fp8((int)hq.x, true);
            f32x2 h2 = __builtin_amdgcn_cvt_pk_f32_fp8((int)hq.y, false);
            f32x2 h3 = __builtin_amdgcn_cvt_pk_f32_fp8((int)hq.y, true);
            float hf[8] = {h0[0], h0[1], h1[0], h1[1], h2[0], h2[1], h3[0], h3[1]};
            float x8[8];
            x8_load(xin, rows + slot, x8);
            #pragma unroll
            for (int j = 0; j < 8; ++j) {
                float v = hf[j] + x8[j];
                vv[i][j] = v;
                s += v; q += v * v;
            }
        }
        #pragma unroll
        for (int o = 1; o < 8; o <<= 1) {
            s += __shfl_xor(s, o, 64);
            q += __shfl_xor(q, o, 64);
        }
        float mu = s * (1.0f / HDIM);
        float var = q * (1.0f / HDIM) - mu * mu;
        float rs = rsqrtf(var + 1e-5f);
        #pragma unroll
        for (int i = 0; i < 4; ++i) {
            int slot = rot + 8 * i;
            int chunk = slot ^ (rr & 7);
            if (LAST) {
                float* xrow = xf32 + (((size_t)(m0 + rr)) << 8);
                f32x4 o0, o1;
                #pragma unroll
                for (int j = 0; j < 4; ++j) {
                    o0[j] = (vv[i][j] - mu) * rs * sGB[0][chunk * 8 + j]
                            + sGB[1][chunk * 8 + j];
                    o1[j] = (vv[i][4 + j] - mu) * rs * sGB[0][chunk * 8 + 4 + j]
                            + sGB[1][chunk * 8 + 4 + j];
                }
                *(f32x4*)&xrow[chunk * 8] = o0;
                *(f32x4*)&xrow[chunk * 8 + 4] = o1;
            } else {
                float ov[8];
                #pragma unroll
                for (int j = 0; j < 8; ++j)
                    ov[j] = (vv[i][j] - mu) * rs * sGB[0][chunk * 8 + j]
                            + sGB[1][chunk * 8 + j];
                x8_store(xout, rows + slot, ov);
            }
        }
    }
}

extern "C" void kernel_launch(void* const* d_in, const int* in_sizes, int n_in,
                              void* d_out, int out_size, void* d_ws, size_t ws_size,
                              hipStream_t stream)
{
    const int*   z    = (const int*)d_in[0];
    const float* feat = (const float*)d_in[1];
    const int*   ei   = (const int*)d_in[2];
    const float* ea   = (const float*)d_in[3];
    const int*   batch= (const int*)d_in[4];
    const float* emb  = (const float*)d_in[5];
    const float* Wf   = (const float*)d_in[6];
    const float* bfv  = (const float*)d_in[7];
    const float* g0   = (const float*)d_in[8];
    const float* b0   = (const float*)d_in[9];
    const float* We   = (const float*)d_in[10];
    const float* be   = (const float*)d_in[11];
    const float* W1   = (const float*)d_in[12];
    const float* b1   = (const float*)d_in[13];
    const float* W2   = (const float*)d_in[14];
    const float* b2   = (const float*)d_in[15];
    const float* lng  = (const float*)d_in[16];
    const float* lnb  = (const float*)d_in[17];

    float* x    = (float*)d_out;
    float* outb = (float*)d_out + (size_t)NN * HDIM;

    const size_t XBYTES = (size_t)NN * 256;           // fp8: 1B/elem
    const size_t EBYTES = (size_t)EE * 256;
    const size_t WBYTES = (size_t)LL * 65536;         // fp8 weights

    char* ws = (char*)d_ws;
    size_t o = 0;
    void* xb0 = (void*)(ws + o); o += XBYTES;
    void* xb1 = (void*)(ws + o); o += XBYTES;
    void* Ubuf = (void*)(ws + o); o += XBYTES;
    float4* eaf = (float4*)(ws + o); o += (size_t)EE * 16;
    int* srcs = (int*)(ws + o); o += (size_t)EE * 4;
    int* off = (int*)(ws + o); o += (size_t)(NN + 4) * 4;
    int* cursor = (int*)(ws + o); o += (size_t)NN * 4;
    int* deg = (int*)(ws + o); o += (size_t)NN * 4;
    int* psum = (int*)(ws + o); o += 1024;
    uchar_t* Wc1 = (uchar_t*)(ws + o); o += WBYTES;
    uchar_t* Wc2 = (uchar_t*)(ws + o); o += WBYTES;
    ushort_t* Wfc = (ushort_t*)(ws + o); o += 16384;
    void* eprec = (void*)(ws + o); o += EBYTES;
    const int use_e = (ws_size >= o) ? 1 : 0;

    prep_w_kernel<<<2048, 256, 0, stream>>>(W1, W2, Wc1, Wc2);
    prep_wf_kernel<<<32, 256, 0, stream>>>(Wf, Wfc);
    batch_out_kernel<<<782, 256, 0, stream>>>(batch, outb);
    node_init_kernel<<<NN / 64, 512, 0, stream>>>(z, feat, emb, Wfc, bfv, g0, b0, xb0);

    hipMemsetAsync(deg, 0, NN * sizeof(int), stream);
    hist_kernel<<<1563, 256, 0, stream>>>(ei, deg);
    scan_blocks_kernel<<<196, 256, 0, stream>>>(deg, off, psum);
    scan_top_kernel<<<1, 256, 0, stream>>>(psum, 196);
    scan_add_kernel<<<782, 256, 0, stream>>>(off, psum, cursor);
    scatter_kernel<<<EE * 32 / 256, 256, 0, stream>>>(ei, ea, We, be, cursor, srcs, eaf, eprec);

    // x ping-pong between xb0/xb1 (fp8); U (fp8) in its own buffer.
    void* xbuf[2] = {xb0, xb1};
    for (int l = 0; l < LL; ++l) {
        void* xin  = xbuf[l & 1];
        void* xout = xbuf[(l + 1) & 1];
        if (use_e)
            agg_kernel<1><<<4096, 256, 0, stream>>>(off, srcs, eprec, eaf, We, be, xin, Ubuf);
        else
            agg_kernel<0><<<4096, 256, 0, stream>>>(off, srcs, eprec, eaf, We, be, xin, Ubuf);
        if (l == LL - 1) {
            mlp_kernel<1><<<NN / 64, 512, 0, stream>>>(
                Ubuf, Wc1 + l * 65536, Wc2 + l * 65536, b1 + l * HDIM, b2 + l * HDIM,
                lng + l * HDIM, lnb + l * HDIM, xin, xout, x);
        } else {
            mlp_kernel<0><<<NN / 64, 512, 0, stream>>>(
                Ubuf, Wc1 + l * 65536, Wc2 + l * 65536, b1 + l * HDIM, b2 + l * HDIM,
                lng + l * HDIM, lnb + l * HDIM, xin, xout, nullptr);
        }
    }
}

// Round 21
// 712.783 us; speedup vs baseline: 1.0318x; 1.0318x over previous
//
#include <hip/hip_runtime.h>
#include <hip/hip_bf16.h>

#define NN 200000
#define EE 400000
#define HDIM 256
#define LL 4
#define FEAT 10

typedef unsigned short ushort_t;
typedef unsigned char uchar_t;
typedef __attribute__((ext_vector_type(8))) short bf16x8;
typedef __attribute__((ext_vector_type(8))) unsigned short u16x8;
typedef __attribute__((ext_vector_type(2))) float f32x2;
typedef __attribute__((ext_vector_type(4))) float f32x4;
typedef __attribute__((ext_vector_type(4))) unsigned int u32x4;

__device__ inline ushort_t f2bf(float f) {
    unsigned int u = __builtin_bit_cast(unsigned int, f);
    return (ushort_t)((u + 0x7fffu + ((u >> 16) & 1u)) >> 16);
}
__device__ inline float bf2f(ushort_t s) {
    unsigned int u = ((unsigned int)s) << 16;
    return __builtin_bit_cast(float, u);
}
__device__ inline float silu_f(float v) { return v / (1.0f + __expf(-v)); }

// ---- x / U / e storage: fp8 e4m3 (8 cols -> uint2 = 8 bytes).
// Row layout: slot s (8-col granule) holds true 8-col chunk s ^ (n&7), s in [0,32).
__device__ inline void x8_load(const void* base, size_t idx, float* f) {
    uint2 v = ((const uint2*)base)[idx];
    f32x2 a0 = __builtin_amdgcn_cvt_pk_f32_fp8((int)v.x, false);
    f32x2 a1 = __builtin_amdgcn_cvt_pk_f32_fp8((int)v.x, true);
    f32x2 a2 = __builtin_amdgcn_cvt_pk_f32_fp8((int)v.y, false);
    f32x2 a3 = __builtin_amdgcn_cvt_pk_f32_fp8((int)v.y, true);
    f[0]=a0[0]; f[1]=a0[1]; f[2]=a1[0]; f[3]=a1[1];
    f[4]=a2[0]; f[5]=a2[1]; f[6]=a3[0]; f[7]=a3[1];
}
__device__ inline void x8_store(void* base, size_t idx, const float* f) {
    int t0 = __builtin_amdgcn_cvt_pk_fp8_f32(f[0], f[1], 0, false);
    t0 = __builtin_amdgcn_cvt_pk_fp8_f32(f[2], f[3], t0, true);
    int t1 = __builtin_amdgcn_cvt_pk_fp8_f32(f[4], f[5], 0, false);
    t1 = __builtin_amdgcn_cvt_pk_fp8_f32(f[6], f[7], t1, true);
    uint2 o; o.x = (unsigned int)t0; o.y = (unsigned int)t1;
    ((uint2*)base)[idx] = o;
}

// ---------------- Wf pre-pack: A-operand fragment layout (bf16), single K=32 chunk
__global__ __launch_bounds__(256) void prep_wf_kernel(
    const float* __restrict__ Wf, ushort_t* __restrict__ Wfc)
{
    int idx = blockIdx.x * 256 + threadIdx.x;   // 8192
    if (idx >= 8192) return;
    int e = idx & 7;
    int lane = (idx >> 3) & 63;
    int nf = (idx >> 9) & 1;
    int w8 = idx >> 10;
    int n = w8 * 32 + nf * 16 + (lane & 15);
    int k = (lane >> 4) * 8 + e;
    Wfc[idx] = (k < FEAT) ? f2bf(Wf[k * HDIM + n]) : (ushort_t)0;
}

// ---------------- node init via MFMA (bf16): xb = fp8(LN(silu(emb[z] + feat@Wf + bf)))
__global__ __launch_bounds__(512, 4) void node_init_kernel(
    const int* __restrict__ z, const float* __restrict__ feat,
    const float* __restrict__ emb, const ushort_t* __restrict__ Wfc,
    const float* __restrict__ bfv, const float* __restrict__ g0,
    const float* __restrict__ b0, void* __restrict__ xb)
{
    __shared__ ushort_t sA[64][256];
    __shared__ float sGB[2][HDIM];
    const int tid = threadIdx.x;
    const int m0 = blockIdx.x * 64;
    const int lane = tid & 63;
    const int w = tid >> 6;
    const int lg = lane >> 4, ll = lane & 15;
    const int cb = w * 32;

    if (tid < HDIM) sGB[0][tid] = g0[tid];
    else sGB[1][tid - HDIM] = b0[tid - HDIM];

    f32x4 bvv[2];
    #pragma unroll
    for (int nf = 0; nf < 2; ++nf)
        bvv[nf] = *(const f32x4*)&bfv[cb + nf * 16 + lg * 4];

    bf16x8 wf[2];
    wf[0] = *(const bf16x8*)(Wfc + w * 1024 + lane * 8);
    wf[1] = *(const bf16x8*)(Wfc + w * 1024 + 512 + lane * 8);

    bf16x8 af[4];
    #pragma unroll
    for (int m = 0; m < 4; ++m) {
        int gr = m0 + m * 16 + ll;
        bf16x8 t = {};
        if (lg == 0) {
            #pragma unroll
            for (int j = 0; j < 8; ++j) t[j] = (short)f2bf(feat[gr * FEAT + j]);
        } else if (lg == 1) {
            t[0] = (short)f2bf(feat[gr * FEAT + 8]);
            t[1] = (short)f2bf(feat[gr * FEAT + 9]);
        }
        af[m] = t;
    }

    f32x4 acc[4][2] = {};
    #pragma unroll
    for (int m = 0; m < 4; ++m)
        #pragma unroll
        for (int nf = 0; nf < 2; ++nf)
            acc[m][nf] = __builtin_amdgcn_mfma_f32_16x16x32_bf16(
                wf[nf], af[m], acc[m][nf], 0, 0, 0);

    #pragma unroll
    for (int m = 0; m < 4; ++m) {
        int r = m * 16 + ll, rx = r & 7;
        int zi = z[m0 + r];
        #pragma unroll
        for (int nf = 0; nf < 2; ++nf) {
            int n0 = cb + nf * 16 + lg * 4;
            f32x4 ev = *(const f32x4*)&emb[(size_t)zi * HDIM + n0];
            int chunk = ((cb + nf * 16) >> 3) + (lg >> 1);
            int celloff = ((chunk ^ rx) << 3) + (lg & 1) * 4;
            ushort4 o;
            o.x = f2bf(silu_f(acc[m][nf][0] + ev[0] + bvv[nf][0]));
            o.y = f2bf(silu_f(acc[m][nf][1] + ev[1] + bvv[nf][1]));
            o.z = f2bf(silu_f(acc[m][nf][2] + ev[2] + bvv[nf][2]));
            o.w = f2bf(silu_f(acc[m][nf][3] + ev[3] + bvv[nf][3]));
            *(ushort4*)&sA[r][celloff] = o;
        }
    }
    __syncthreads();

    {
        int rr = tid >> 3, kk = tid & 7;
        int rot = (kk + rr) & 7;
        u16x8 v8[4];
        float s = 0.f, q = 0.f;
        #pragma unroll
        for (int i = 0; i < 4; ++i) {
            int slot = rot + 8 * i;
            v8[i] = *(const u16x8*)&sA[rr][slot << 3];
            #pragma unroll
            for (int j = 0; j < 8; ++j) {
                float v = bf2f(v8[i][j]);
                s += v; q += v * v;
            }
        }
        #pragma unroll
        for (int o = 1; o < 8; o <<= 1) {
            s += __shfl_xor(s, o, 64);
            q += __shfl_xor(q, o, 64);
        }
        float mu = s * (1.0f / HDIM);
        float var = q * (1.0f / HDIM) - mu * mu;
        float rs = rsqrtf(var + 1e-5f);
        size_t rows = ((size_t)(m0 + rr)) << 5;
        #pragma unroll
        for (int i = 0; i < 4; ++i) {
            int slot = rot + 8 * i;
            int chunk = slot ^ (rr & 7);
            float ov[8];
            #pragma unroll
            for (int j = 0; j < 8; ++j)
                ov[j] = (bf2f(v8[i][j]) - mu) * rs * sGB[0][chunk * 8 + j]
                        + sGB[1][chunk * 8 + j];
            x8_store(xb, rows + slot, ov);
        }
    }
}

__global__ __launch_bounds__(256) void batch_out_kernel(
    const int* __restrict__ batch, float* __restrict__ out)
{
    int i = blockIdx.x * 256 + threadIdx.x;
    if (i < NN) out[i] = (float)batch[i];
}

// ---------------- CSR build
__global__ __launch_bounds__(256) void hist_kernel(const int* __restrict__ ei, int* __restrict__ deg)
{
    int i = blockIdx.x * 256 + threadIdx.x;
    if (i < EE) atomicAdd(&deg[ei[EE + i]], 1);
}

__global__ __launch_bounds__(256) void scan_blocks_kernel(
    const int* __restrict__ deg, int* __restrict__ off, int* __restrict__ psum)
{
    int blk = blockIdx.x, t = threadIdx.x;
    int base = blk * 1024 + t * 4;
    int v[4];
    #pragma unroll
    for (int i = 0; i < 4; ++i) v[i] = (base + i < NN) ? deg[base + i] : 0;
    int s = v[0] + v[1] + v[2] + v[3];
    int lane = t & 63, w = t >> 6;
    int ps = s;
    #pragma unroll
    for (int o = 1; o < 64; o <<= 1) { int u = __shfl_up(ps, o, 64); if (lane >= o) ps += u; }
    __shared__ int wt[4];
    if (lane == 63) wt[w] = ps;
    __syncthreads();
    int wbase = 0;
    for (int k = 0; k < w; ++k) wbase += wt[k];
    int run = wbase + ps - s;
    #pragma unroll
    for (int i = 0; i < 4; ++i) {
        if (base + i < NN) off[base + i] = run;
        run += v[i];
    }
    if (t == 255) psum[blk] = wbase + ps;
}

__global__ __launch_bounds__(256) void scan_top_kernel(int* __restrict__ psum, int nb)
{
    int t = threadIdx.x;
    int v = (t < nb) ? psum[t] : 0;
    int lane = t & 63, w = t >> 6;
    int ps = v;
    #pragma unroll
    for (int o = 1; o < 64; o <<= 1) { int u = __shfl_up(ps, o, 64); if (lane >= o) ps += u; }
    __shared__ int wt[4];
    if (lane == 63) wt[w] = ps;
    __syncthreads();
    int wbase = 0;
    for (int k = 0; k < w; ++k) wbase += wt[k];
    if (t < nb) psum[t] = wbase + ps - v;
}

__global__ __launch_bounds__(256) void scan_add_kernel(
    int* __restrict__ off, const int* __restrict__ psum, int* __restrict__ cursor)
{
    int i = blockIdx.x * 256 + threadIdx.x;
    if (i < NN) {
        int o = off[i] + psum[i >> 10];
        off[i] = o;
        cursor[i] = o;
        if (i == NN - 1) off[NN] = EE;
    }
}

__global__ __launch_bounds__(256) void scatter_kernel(
    const int* __restrict__ ei, const float* __restrict__ ea,
    int* __restrict__ cursor, int* __restrict__ srcs, float4* __restrict__ eaf)
{
    int i = blockIdx.x * 256 + threadIdx.x;
    if (i < EE) {
        int dst = ei[EE + i];
        int pos = atomicAdd(&cursor[dst], 1);
        srcs[pos] = ei[i];
        eaf[pos] = ((const float4*)ea)[i];
    }
}

// ---------------- edge MLP (layer-invariant): e = fp8(silu(eaf@We + be)), CSR order
// sequential reads AND sequential writes (coalesced streams)
__global__ __launch_bounds__(256) void edge_mlp_kernel(
    const float4* __restrict__ eaf, const float* __restrict__ We,
    const float* __restrict__ be, void* __restrict__ eout)
{
    int p = (blockIdx.x * 256 + threadIdx.x) >> 5;
    if (p >= EE) return;
    int nl = threadIdx.x & 31, c0 = nl * 8;
    float4 av = eaf[p];
    float v[8];
    #pragma unroll
    for (int j = 0; j < 8; ++j) {
        float t = be[c0 + j] + av.x * We[c0 + j] + av.y * We[HDIM + c0 + j]
                + av.z * We[2 * HDIM + c0 + j] + av.w * We[3 * HDIM + c0 + j];
        v[j] = silu_f(t);
    }
    x8_store(eout, ((size_t)p << 5) + nl, v);
}

// ---------------- weights: W[l][k][n] f32 -> chunk-major per-wave fragment layout, fp8
__global__ __launch_bounds__(256) void prep_w_kernel(
    const float* __restrict__ W1, const float* __restrict__ W2,
    uchar_t* __restrict__ Wc1, uchar_t* __restrict__ Wc2)
{
    int idx = blockIdx.x * 256 + threadIdx.x;   // 2 * 4 * 65536
    int which = idx >> 18;
    int rem = idx & 0x3FFFF;
    int l = rem >> 16;
    int t = rem & 0xFFFF;
    int e = t & 7;
    int lane = (t >> 3) & 63;
    int nf = (t >> 9) & 1;
    int w8 = (t >> 10) & 7;
    int c = (t >> 13) & 7;
    int n = w8 * 32 + nf * 16 + (lane & 15);
    int k = c * 32 + (lane >> 4) * 8 + e;
    const float* W = which ? W2 : W1;
    float v = W[l * 65536 + k * 256 + n];
    uchar_t* Wc = which ? Wc2 : Wc1;
    int pk = __builtin_amdgcn_cvt_pk_fp8_f32(v, v, 0, false);
    Wc[rem] = (uchar_t)(pk & 0xFF);
}

// ---------------- aggregation: U = fp8(x_self + sum relu(x[src]+e)); 32-lane groups
template<int USE_E>
__global__ __launch_bounds__(256) void agg_kernel(
    const int* __restrict__ off, const int* __restrict__ srcs,
    const void* __restrict__ eprec, const float4* __restrict__ eaf,
    const float* __restrict__ We, const float* __restrict__ be,
    const void* __restrict__ xin, void* __restrict__ U)
{
    const int gstride = (gridDim.x * 256) >> 5;
    const int gid0 = (blockIdx.x * 256 + threadIdx.x) >> 5;
    const int nl = threadIdx.x & 31, c0 = nl * 8;
    float wv[4][8], bev[8];
    if (!USE_E) {
        #pragma unroll
        for (int r4 = 0; r4 < 4; ++r4)
            #pragma unroll
            for (int j = 0; j < 8; ++j) wv[r4][j] = We[r4 * HDIM + c0 + j];
        #pragma unroll
        for (int j = 0; j < 8; ++j) bev[j] = be[c0 + j];
    }

    for (int n = gid0; n < NN; n += gstride) {
        float acc[8];
        x8_load(xin, (((size_t)n) << 5) + (nl ^ (n & 7)), acc);
        int beg = off[n], end = off[n + 1];
        if (USE_E) {
            for (int p = beg; p < end; ++p) {
                int src = srcs[p];
                float xg[8], ev[8];
                x8_load(xin, (((size_t)src) << 5) + (nl ^ (src & 7)), xg);
                x8_load(eprec, ((size_t)p << 5) + nl, ev);
                #pragma unroll
                for (int j = 0; j < 8; ++j)
                    acc[j] += fmaxf(xg[j] + ev[j], 0.f);
            }
        } else {
            for (int p = beg; p < end; ++p) {
                int src = srcs[p];
                float4 av = eaf[p];
                float xg[8];
                x8_load(xin, (((size_t)src) << 5) + (nl ^ (src & 7)), xg);
                #pragma unroll
                for (int j = 0; j < 8; ++j) {
                    float e = silu_f(bev[j] + av.x * wv[0][j] + av.y * wv[1][j]
                                            + av.z * wv[2][j] + av.w * wv[3][j]);
                    acc[j] += fmaxf(xg[j] + e, 0.f);
                }
            }
        }
        x8_store(U, (((size_t)n) << 5) + (nl ^ (n & 7)), acc);
    }
}

// ---------------- MLP + LN, full fp8 GEMM path; 2-deep weight prefetch (same 2 buffers)
template<int LAST>
__global__ __launch_bounds__(512, 4) void mlp_kernel(
    const void* __restrict__ U, const uchar_t* __restrict__ Wc1,
    const uchar_t* __restrict__ Wc2, const float* __restrict__ b1,
    const float* __restrict__ b2, const float* __restrict__ lng,
    const float* __restrict__ lnb, const void* __restrict__ xin,
    void* __restrict__ xout, float* __restrict__ xf32)
{
    __shared__ uchar_t sF[64][256];      // 16KB fp8 cells: U -> t -> h
    __shared__ float sGB[2][HDIM];       // 2KB gamma/beta
    const int tid = threadIdx.x;
    const int m0 = blockIdx.x * 64;
    const int lane = tid & 63;
    const int w = tid >> 6;
    const int lg = lane >> 4, ll = lane & 15;
    const int cb = w * 32;

    if (tid < HDIM) sGB[0][tid] = lng[tid];
    else sGB[1][tid - HDIM] = lnb[tid - HDIM];

    f32x4 bv1v[2], bv2v[2];
    #pragma unroll
    for (int nf = 0; nf < 2; ++nf) {
        int nb = cb + nf * 16 + lg * 4;
        bv1v[nf] = *(const f32x4*)&b1[nb];
        bv2v[nf] = *(const f32x4*)&b2[nb];
    }

    // ---- stage U tile: pure 8B copy (fp8 global -> fp8 LDS, layout identical)
    {
        const uint2* Uq = (const uint2*)U + (((size_t)m0) << 5);
        uint2* sQ = (uint2*)&sF[0][0];
        #pragma unroll
        for (int it = 0; it < 4; ++it) {
            int idx = tid + it * 512;
            sQ[idx] = Uq[idx];
        }
    }
    __syncthreads();

    f32x4 acc[4][2] = {};
    const uchar_t* wp1 = Wc1 + w * 1024 + lane * 8;
    const uchar_t* wp2 = Wc2 + w * 1024 + lane * 8;
    long long wbuf[2][2];
    wbuf[0][0] = *(const long long*)(wp1);
    wbuf[0][1] = *(const long long*)(wp1 + 512);
    wbuf[1][0] = *(const long long*)(wp1 + 8192);
    wbuf[1][1] = *(const long long*)(wp1 + 8192 + 512);

    // ---- GEMM1 (fp8): use wbuf[p&1]; then load chunk p+2 into wbuf[p&1]
    #pragma unroll
    for (int p = 0; p < 8; ++p) {
        long long af[4];
        #pragma unroll
        for (int m = 0; m < 4; ++m) {
            int r = m * 16 + ll;
            af[m] = *(const long long*)&sF[r][(((p * 4 + lg) ^ (r & 7)) << 3)];
        }
        #pragma unroll
        for (int m = 0; m < 4; ++m)
            #pragma unroll
            for (int nf = 0; nf < 2; ++nf)
                acc[m][nf] = __builtin_amdgcn_mfma_f32_16x16x32_fp8_fp8(
                    wbuf[p & 1][nf], af[m], acc[m][nf], 0, 0, 0);
        const uchar_t* nsrc = (p < 6) ? (wp1 + (p + 2) * 8192) : (wp2 + (p - 6) * 8192);
        wbuf[p & 1][0] = *(const long long*)(nsrc);
        wbuf[p & 1][1] = *(const long long*)(nsrc + 512);
    }
    __syncthreads();   // all waves done reading sF(U)

    // ---- t = fp8(silu(acc + b1)) -> sF (4B packs); reset acc
    #pragma unroll
    for (int m = 0; m < 4; ++m) {
        int r = m * 16 + ll, rx = r & 7;
        #pragma unroll
        for (int nf = 0; nf < 2; ++nf) {
            int chunk = ((cb + nf * 16) >> 3) + (lg >> 1);
            int boff = ((chunk ^ rx) << 3) + (lg & 1) * 4;
            float v0 = silu_f(acc[m][nf][0] + bv1v[nf][0]);
            float v1 = silu_f(acc[m][nf][1] + bv1v[nf][1]);
            float v2 = silu_f(acc[m][nf][2] + bv1v[nf][2]);
            float v3 = silu_f(acc[m][nf][3] + bv1v[nf][3]);
            int pk = __builtin_amdgcn_cvt_pk_fp8_f32(v0, v1, 0, false);
            pk = __builtin_amdgcn_cvt_pk_fp8_f32(v2, v3, pk, true);
            *(unsigned int*)&sF[r][boff] = (unsigned int)pk;
            acc[m][nf][0] = 0.f; acc[m][nf][1] = 0.f;
            acc[m][nf][2] = 0.f; acc[m][nf][3] = 0.f;
        }
    }
    __syncthreads();   // t visible

    // ---- GEMM2 (fp8): wbuf holds W2 c0,c1; load p+2 after use
    #pragma unroll
    for (int p = 0; p < 8; ++p) {
        long long af[4];
        #pragma unroll
        for (int m = 0; m < 4; ++m) {
            int r = m * 16 + ll;
            af[m] = *(const long long*)&sF[r][(((p * 4 + lg) ^ (r & 7)) << 3)];
        }
        #pragma unroll
        for (int m = 0; m < 4; ++m)
            #pragma unroll
            for (int nf = 0; nf < 2; ++nf)
                acc[m][nf] = __builtin_amdgcn_mfma_f32_16x16x32_fp8_fp8(
                    wbuf[p & 1][nf], af[m], acc[m][nf], 0, 0, 0);
        if (p < 6) {
            const uchar_t* nsrc = wp2 + (p + 2) * 8192;
            wbuf[p & 1][0] = *(const long long*)(nsrc);
            wbuf[p & 1][1] = *(const long long*)(nsrc + 512);
        }
    }
    __syncthreads();   // all waves done reading sF(t)

    // ---- h = fp8(acc + b2) -> sF cells
    #pragma unroll
    for (int m = 0; m < 4; ++m) {
        int r = m * 16 + ll, rx = r & 7;
        #pragma unroll
        for (int nf = 0; nf < 2; ++nf) {
            int chunk = ((cb + nf * 16) >> 3) + (lg >> 1);
            int boff = ((chunk ^ rx) << 3) + (lg & 1) * 4;
            float v0 = acc[m][nf][0] + bv2v[nf][0];
            float v1 = acc[m][nf][1] + bv2v[nf][1];
            float v2 = acc[m][nf][2] + bv2v[nf][2];
            float v3 = acc[m][nf][3] + bv2v[nf][3];
            int pk = __builtin_amdgcn_cvt_pk_fp8_f32(v0, v1, 0, false);
            pk = __builtin_amdgcn_cvt_pk_fp8_f32(v2, v3, pk, true);
            *(unsigned int*)&sF[r][boff] = (unsigned int)pk;
        }
    }
    __syncthreads();   // h visible

    // ---- row-pass LN: 8 thr/row, rotation swizzle; residual x from global (fp8)
    {
        int rr = tid >> 3, kk = tid & 7;
        int rot = (kk + rr) & 7;
        size_t rows = ((size_t)(m0 + rr)) << 5;
        float vv[4][8];
        float s = 0.f, q = 0.f;
        #pragma unroll
        for (int i = 0; i < 4; ++i) {
            int slot = rot + 8 * i;
            uint2 hq = *(const uint2*)&sF[rr][slot << 3];
            f32x2 h0 = __builtin_amdgcn_cvt_pk_f32_fp8((int)hq.x, false);
            f32x2 h1 = __builtin_amdgcn_cvt_pk_f32_fp8((int)hq.x, true);
            f32x2 h2 = __builtin_amdgcn_cvt_pk_f32_fp8((int)hq.y, false);
            f32x2 h3 = __builtin_amdgcn_cvt_pk_f32_fp8((int)hq.y, true);
            float hf[8] = {h0[0], h0[1], h1[0], h1[1], h2[0], h2[1], h3[0], h3[1]};
            float x8[8];
            x8_load(xin, rows + slot, x8);
            #pragma unroll
            for (int j = 0; j < 8; ++j) {
                float v = hf[j] + x8[j];
                vv[i][j] = v;
                s += v; q += v * v;
            }
        }
        #pragma unroll
        for (int o = 1; o < 8; o <<= 1) {
            s += __shfl_xor(s, o, 64);
            q += __shfl_xor(q, o, 64);
        }
        float mu = s * (1.0f / HDIM);
        float var = q * (1.0f / HDIM) - mu * mu;
        float rs = rsqrtf(var + 1e-5f);
        #pragma unroll
        for (int i = 0; i < 4; ++i) {
            int slot = rot + 8 * i;
            int chunk = slot ^ (rr & 7);
            if (LAST) {
                float* xrow = xf32 + (((size_t)(m0 + rr)) << 8);
                f32x4 o0, o1;
                #pragma unroll
                for (int j = 0; j < 4; ++j) {
                    o0[j] = (vv[i][j] - mu) * rs * sGB[0][chunk * 8 + j]
                            + sGB[1][chunk * 8 + j];
                    o1[j] = (vv[i][4 + j] - mu) * rs * sGB[0][chunk * 8 + 4 + j]
                            + sGB[1][chunk * 8 + 4 + j];
                }
                *(f32x4*)&xrow[chunk * 8] = o0;
                *(f32x4*)&xrow[chunk * 8 + 4] = o1;
            } else {
                float ov[8];
                #pragma unroll
                for (int j = 0; j < 8; ++j)
                    ov[j] = (vv[i][j] - mu) * rs * sGB[0][chunk * 8 + j]
                            + sGB[1][chunk * 8 + j];
                x8_store(xout, rows + slot, ov);
            }
        }
    }
}

extern "C" void kernel_launch(void* const* d_in, const int* in_sizes, int n_in,
                              void* d_out, int out_size, void* d_ws, size_t ws_size,
                              hipStream_t stream)
{
    const int*   z    = (const int*)d_in[0];
    const float* feat = (const float*)d_in[1];
    const int*   ei   = (const int*)d_in[2];
    const float* ea   = (const float*)d_in[3];
    const int*   batch= (const int*)d_in[4];
    const float* emb  = (const float*)d_in[5];
    const float* Wf   = (const float*)d_in[6];
    const float* bfv  = (const float*)d_in[7];
    const float* g0   = (const float*)d_in[8];
    const float* b0   = (const float*)d_in[9];
    const float* We   = (const float*)d_in[10];
    const float* be   = (const float*)d_in[11];
    const float* W1   = (const float*)d_in[12];
    const float* b1   = (const float*)d_in[13];
    const float* W2   = (const float*)d_in[14];
    const float* b2   = (const float*)d_in[15];
    const float* lng  = (const float*)d_in[16];
    const float* lnb  = (const float*)d_in[17];

    float* x    = (float*)d_out;
    float* outb = (float*)d_out + (size_t)NN * HDIM;

    const size_t XBYTES = (size_t)NN * 256;           // fp8: 1B/elem
    const size_t EBYTES = (size_t)EE * 256;
    const size_t WBYTES = (size_t)LL * 65536;         // fp8 weights

    char* ws = (char*)d_ws;
    size_t o = 0;
    void* xb0 = (void*)(ws + o); o += XBYTES;
    void* xb1 = (void*)(ws + o); o += XBYTES;
    void* Ubuf = (void*)(ws + o); o += XBYTES;
    float4* eaf = (float4*)(ws + o); o += (size_t)EE * 16;
    int* srcs = (int*)(ws + o); o += (size_t)EE * 4;
    int* off = (int*)(ws + o); o += (size_t)(NN + 4) * 4;
    int* cursor = (int*)(ws + o); o += (size_t)NN * 4;
    int* deg = (int*)(ws + o); o += (size_t)NN * 4;
    int* psum = (int*)(ws + o); o += 1024;
    uchar_t* Wc1 = (uchar_t*)(ws + o); o += WBYTES;
    uchar_t* Wc2 = (uchar_t*)(ws + o); o += WBYTES;
    ushort_t* Wfc = (ushort_t*)(ws + o); o += 16384;
    void* eprec = (void*)(ws + o); o += EBYTES;
    const int use_e = (ws_size >= o) ? 1 : 0;

    prep_w_kernel<<<2048, 256, 0, stream>>>(W1, W2, Wc1, Wc2);
    prep_wf_kernel<<<32, 256, 0, stream>>>(Wf, Wfc);
    batch_out_kernel<<<782, 256, 0, stream>>>(batch, outb);
    node_init_kernel<<<NN / 64, 512, 0, stream>>>(z, feat, emb, Wfc, bfv, g0, b0, xb0);

    hipMemsetAsync(deg, 0, NN * sizeof(int), stream);
    hist_kernel<<<1563, 256, 0, stream>>>(ei, deg);
    scan_blocks_kernel<<<196, 256, 0, stream>>>(deg, off, psum);
    scan_top_kernel<<<1, 256, 0, stream>>>(psum, 196);
    scan_add_kernel<<<782, 256, 0, stream>>>(off, psum, cursor);
    scatter_kernel<<<1563, 256, 0, stream>>>(ei, ea, cursor, srcs, eaf);
    if (use_e)
        edge_mlp_kernel<<<EE / 8, 256, 0, stream>>>(eaf, We, be, eprec);

    // x ping-pong between xb0/xb1 (fp8); U (fp8) in its own buffer.
    void* xbuf[2] = {xb0, xb1};
    for (int l = 0; l < LL; ++l) {
        void* xin  = xbuf[l & 1];
        void* xout = xbuf[(l + 1) & 1];
        if (use_e)
            agg_kernel<1><<<4096, 256, 0, stream>>>(off, srcs, eprec, eaf, We, be, xin, Ubuf);
        else
            agg_kernel<0><<<4096, 256, 0, stream>>>(off, srcs, eprec, eaf, We, be, xin, Ubuf);
        if (l == LL - 1) {
            mlp_kernel<1><<<NN / 64, 512, 0, stream>>>(
                Ubuf, Wc1 + l * 65536, Wc2 + l * 65536, b1 + l * HDIM, b2 + l * HDIM,
                lng + l * HDIM, lnb + l * HDIM, xin, xout, x);
        } else {
            mlp_kernel<0><<<NN / 64, 512, 0, stream>>>(
                Ubuf, Wc1 + l * 65536, Wc2 + l * 65536, b1 + l * HDIM, b2 + l * HDIM,
                lng + l * HDIM, lnb + l * HDIM, xin, xout, nullptr);
        }
    }
}